// Round 10
// baseline (743.235 us; speedup 1.0000x reference)
//
#include <hip/hip_runtime.h>

typedef unsigned short u16;
typedef __attribute__((ext_vector_type(8))) short bfrag8;   // 8 bf16 (4 VGPR)
typedef __attribute__((ext_vector_type(4))) float facc4;    // 4 f32 accum

#define SCALEF 0.08838834764831845f   // 1/sqrt(128)
#define LAMV   0.9f

__device__ __forceinline__ u16 f2bf(float f) {
    union { float f; unsigned u; } c; c.f = f;
    unsigned r = 0x7fffu + ((c.u >> 16) & 1u);
    return (u16)((c.u + r) >> 16);
}
__device__ __forceinline__ float bf2f(u16 h) {
    union { unsigned u; float f; } c; c.u = ((unsigned)h) << 16;
    return c.f;
}

__device__ __forceinline__ void gll16(const u16* g, u16* l) {
    __builtin_amdgcn_global_load_lds(
        (const __attribute__((address_space(1))) void*)g,
        (__attribute__((address_space(3))) void*)l, 16, 0, 0);
}

// ---------------------------------------------------------------- transpose
// NT loads (r6/r8 A/B: removing them cost ~55us in the non-gemm remainder)
__global__ __launch_bounds__(256) void transpose_f2b(const float* __restrict__ src,
                                                     u16* __restrict__ dst, int R, int C) {
    __shared__ float tile[64][65];
    int c0 = blockIdx.x * 64, r0 = blockIdx.y * 64;
    int t = threadIdx.x, tc = t & 63, tg = t >> 6;
#pragma unroll
    for (int i = 0; i < 16; ++i) {
        int rr = i * 4 + tg;
        tile[rr][tc] = __builtin_nontemporal_load(&src[(size_t)(r0 + rr) * C + c0 + tc]);
    }
    __syncthreads();
#pragma unroll
    for (int i = 0; i < 16; ++i) {
        int cc = i * 4 + tg;
        dst[(size_t)(c0 + cc) * R + r0 + tc] = f2bf(tile[tc][cc]);
    }
}

// ------------------------------------------------------------ embedding+ctx
__global__ __launch_bounds__(256) void embed_ctx(const int* __restrict__ x,
                                                 const float* __restrict__ emb,
                                                 u16* __restrict__ ctx) {
    int row = blockIdx.x;            // 0..4095
    int b = row >> 11, s = row & 2047;
    int t = threadIdx.x;
    float a0 = 0, a1 = 0, a2 = 0, a3 = 0;
    for (int off = 0; off < 4; ++off) {
        int ss = s - off;
        if (ss < 0) break;
        int tok = x[b * 2048 + ss];
        float4 v = ((const float4*)(emb + (size_t)tok * 1024))[t];
        a0 += v.x; a1 += v.y; a2 += v.z; a3 += v.w;
    }
    ushort4 w = make_ushort4(f2bf(a0), f2bf(a1), f2bf(a2), f2bf(a3));
    *(ushort4*)(ctx + (size_t)row * 1024 + t * 4) = w;
}

// ------------------------------------------- xmean partial sums (128 blocks)
__global__ __launch_bounds__(256) void xmean_part(const u16* __restrict__ ctx,
                                                  float* __restrict__ xpart) {
    int blk = blockIdx.x;            // bc*8 + g
    int bc = blk >> 3, g = blk & 7;
    int t = threadIdx.x;
    int row0 = (bc >> 3) * 2048 + (bc & 7) * 256 + g * 32;
    float a0 = 0, a1 = 0, a2 = 0, a3 = 0;
    for (int i = 0; i < 32; ++i) {
        ushort4 v = *(const ushort4*)(ctx + (size_t)(row0 + i) * 1024 + t * 4);
        a0 += bf2f(v.x); a1 += bf2f(v.y); a2 += bf2f(v.z); a3 += bf2f(v.w);
    }
    *(float4*)(xpart + (size_t)blk * 1024 + t * 4) = make_float4(a0, a1, a2, a3);
}

// --------------------------------------------------- EMA state + bypass term
__global__ __launch_bounds__(256) void states_k(const float* __restrict__ xpart,
                                                const float* __restrict__ Ub,
                                                const float* __restrict__ Vb,
                                                float* __restrict__ stbyp) {
    int b = blockIdx.x;
    int t = threadIdx.x, lane = t & 63, wave = t >> 6;
    __shared__ float xm[8][1024];
    __shared__ float byp[8][8];
    for (int idx = t; idx < 8 * 1024; idx += 256) {
        int c = idx >> 10, d = idx & 1023;
        float s = 0.f;
#pragma unroll
        for (int g = 0; g < 8; ++g)
            s += xpart[((size_t)(b * 8 + c) * 8 + g) * 1024 + d];
        xm[c][d] = s * (1.f / 256.f);
    }
    if (t < 8) byp[0][t] = 0.f;
    __syncthreads();
    for (int p = wave; p < 56; p += 4) {
        int c = 1 + (p >> 3), kr = p & 7;
        float s = 0;
        for (int d = lane; d < 1024; d += 64) s += xm[c - 1][d] * Ub[d * 8 + kr];
#pragma unroll
        for (int o = 32; o; o >>= 1) s += __shfl_down(s, o, 64);
        if (lane == 0) byp[c][kr] = s;
    }
    __syncthreads();
    for (int d = t; d < 1024; d += 256) {
        float st = 0.f;
        for (int c = 0; c < 8; ++c) {
            float bv = 0.f;
#pragma unroll
            for (int kr = 0; kr < 8; ++kr) bv += byp[c][kr] * Vb[kr * 1024 + d];
            stbyp[((size_t)b * 8 + c) * 1024 + d] = st + bv;
            st = LAMV * st + (1.0f - LAMV) * xm[c][d];
        }
    }
}

// --------------------------------------------------------------- GEMM core (128^2, small ops)
struct TileSrc { const u16* a; int lda; const u16* b; int ldb; };

template <class Sel, class Epi>
__global__ __launch_bounds__(256) void gemm_k(Sel sel, Epi epi, int KT) {
    __shared__ u16 As[8192];
    __shared__ u16 Bs[8192];
    int t = threadIdx.x, lane = t & 63, wave = t >> 6;
    int wm = wave >> 1, wn = wave & 1;
    int m0 = blockIdx.x * 128, n0 = blockIdx.y * 128, bc = blockIdx.z;

    facc4 acc[4][4];
#pragma unroll
    for (int i = 0; i < 4; ++i)
#pragma unroll
        for (int j = 0; j < 4; ++j) acc[i][j] = (facc4){0.f, 0.f, 0.f, 0.f};

    for (int kt = 0; kt < KT; ++kt) {
        TileSrc s = sel(m0, n0, bc, kt);
#pragma unroll
        for (int it = 0; it < 4; ++it) {
            int q = (it * 4 + wave) * 64 + lane;
            int L = q << 4;                        // linear LDS byte
            int r = L >> 7;                        // tile row
            int cp = ((L >> 4) & 7) ^ (r & 7);     // inverse-swizzled k-chunk
            const u16* ga = s.a + (size_t)r * s.lda + cp * 8;
            const u16* gb = s.b + (size_t)r * s.ldb + cp * 8;
            gll16(ga, As + (size_t)(it * 4 + wave) * 512);
            gll16(gb, Bs + (size_t)(it * 4 + wave) * 512);
        }
        __syncthreads();
#pragma unroll
        for (int kk = 0; kk < 2; ++kk) {
            bfrag8 af[4], bfr[4];
#pragma unroll
            for (int i = 0; i < 4; ++i) {
                int row = wm * 64 + i * 16 + (lane & 15);
                int off = (row << 7) + kk * 64 + ((lane >> 4) << 4);
                off ^= (row & 7) << 4;
                af[i] = *(const bfrag8*)((const char*)As + off);
            }
#pragma unroll
            for (int j = 0; j < 4; ++j) {
                int row = wn * 64 + j * 16 + (lane & 15);
                int off = (row << 7) + kk * 64 + ((lane >> 4) << 4);
                off ^= (row & 7) << 4;
                bfr[j] = *(const bfrag8*)((const char*)Bs + off);
            }
#pragma unroll
            for (int i = 0; i < 4; ++i)
#pragma unroll
                for (int j = 0; j < 4; ++j)
                    acc[i][j] = __builtin_amdgcn_mfma_f32_16x16x32_bf16(af[i], bfr[j], acc[i][j], 0, 0, 0);
        }
        __syncthreads();
    }
#pragma unroll
    for (int i = 0; i < 4; ++i)
#pragma unroll
        for (int j = 0; j < 4; ++j) {
            int row0 = m0 + wm * 64 + i * 16 + ((lane >> 4) << 2);
            int col  = n0 + wn * 64 + j * 16 + (lane & 15);
            epi.store(bc, row0, col, acc[i][j]);
        }
}

// --------------------------------------------------------------- selectors
struct SelPlain {
    const u16 *A, *B; int lda, ldb;
    __device__ TileSrc operator()(int m0, int n0, int bc, int kt) const {
        return TileSrc{A + (size_t)m0 * lda + kt * 64, lda,
                       B + (size_t)n0 * ldb + kt * 64, ldb};
    }
};
struct SelKtKV {
    const u16 *Kt, *Vt;
    __device__ TileSrc operator()(int m0, int n0, int bc, int kt) const {
        int cb = (bc >> 3) * 2048 + (bc & 7) * 256;
        const u16* a = Kt + (size_t)m0 * 4096 + cb + kt * 64;
        const u16* b = (n0 < 1024 ? Vt + (size_t)n0 * 4096
                                  : Kt + (size_t)(n0 - 1024) * 4096) + cb + kt * 64;
        return TileSrc{a, 4096, b, 4096};
    }
};
struct SelComb {
    const u16 *Acat, *Vt, *SstT;
    __device__ TileSrc operator()(int m0, int n0, int bc, int kt) const {
        int cb = (bc >> 3) * 2048 + (bc & 7) * 256;
        const u16* a = Acat + (size_t)(cb + m0) * 384 + kt * 64;
        const u16* b; int ldb;
        if (kt < 4) { b = Vt + (size_t)n0 * 4096 + cb + kt * 64; ldb = 4096; }
        else        { b = SstT + ((size_t)bc * 1024 + n0) * 128 + (kt - 4) * 64; ldb = 128; }
        return TileSrc{a, 384, b, ldb};
    }
};

// --------------------------------------------------------------- epilogues
struct EpiQK {
    u16 *Acat, *Kt;
    __device__ void store(int bc, int row0, int col, facc4 v) const {
        float p[4];
#pragma unroll
        for (int j = 0; j < 4; ++j) { float x = v[j]; p[j] = x > 0.f ? x + 1.f : __expf(x); }
        if (col < 128) {
#pragma unroll
            for (int j = 0; j < 4; ++j) Acat[(size_t)(row0 + j) * 384 + 256 + col] = f2bf(p[j]);
        } else {
            ushort4 w = make_ushort4(f2bf(p[0]), f2bf(p[1]), f2bf(p[2]), f2bf(p[3]));
            *(ushort4*)(Kt + (size_t)(col - 128) * 4096 + row0) = w;
        }
    }
};
struct EpiVt {
    u16* Vt;
    __device__ void store(int bc, int row0, int col, facc4 v) const {
        ushort4 w = make_ushort4(f2bf(v[0]), f2bf(v[1]), f2bf(v[2]), f2bf(v[3]));
        *(ushort4*)(Vt + (size_t)col * 4096 + row0) = w;
    }
};
struct EpiKtKV {
    float *KtVp, *Mp;
    __device__ void store(int bc, int row0, int col, facc4 v) const {
        if (col < 1024) {
            float* p = KtVp + (size_t)bc * 131072;
#pragma unroll
            for (int j = 0; j < 4; ++j) p[(size_t)(row0 + j) * 1024 + col] = v[j] * SCALEF;
        } else {
            float* p = Mp + (size_t)bc * 16384;
#pragma unroll
            for (int j = 0; j < 4; ++j) p[(size_t)(row0 + j) * 128 + (col - 1024)] = v[j] * SCALEF;
        }
    }
};
struct EpiComb {
    u16* outp; const float* stbyp;
    __device__ void store(int bc, int row0, int col, facc4 v) const {
        int cb = (bc >> 3) * 2048 + (bc & 7) * 256;
        float sb = stbyp[(size_t)bc * 1024 + col];
#pragma unroll
        for (int j = 0; j < 4; ++j) outp[(size_t)(cb + row0 + j) * 1024 + col] = f2bf(v[j] + sb);
    }
};
struct EpiF32 {
    float* C; int ld;
    __device__ void store(int bc, int row0, int col, facc4 v) const {
#pragma unroll
        for (int j = 0; j < 4; ++j) C[(size_t)(row0 + j) * ld + col] = v[j];
    }
};

// ------------------------------------------------------ intra-chunk attention
__global__ __launch_bounds__(256) void attn_k(const u16* __restrict__ Acat,
                                              const u16* __restrict__ Kt,
                                              u16* __restrict__ AcatOut) {
    int bx = blockIdx.x, by = blockIdx.y, bc = blockIdx.z;
    int cb = (bc >> 3) * 2048 + (bc & 7) * 256;
    int i0 = bx * 64, j0 = by * 64;
    int t = threadIdx.x, ti = t >> 4, tj = t & 15;
    if (by > bx) {
        ushort4 z = make_ushort4(0, 0, 0, 0);
#pragma unroll
        for (int ii = 0; ii < 4; ++ii) {
            int gi = i0 + ti * 4 + ii;
            *(ushort4*)(AcatOut + (size_t)(cb + gi) * 384 + j0 + tj * 4) = z;
        }
        return;
    }
    __shared__ float qs[64][128];
    __shared__ float ks[128][64];
#pragma unroll
    for (int i = 0; i < 8; ++i) {
        int idx = i * 256 + t;
        int rr = idx >> 5, c4 = idx & 31;
        ushort4 v = *(const ushort4*)(Acat + (size_t)(cb + i0 + rr) * 384 + 256 + c4 * 4);
        qs[rr][c4 * 4 + 0] = bf2f(v.x); qs[rr][c4 * 4 + 1] = bf2f(v.y);
        qs[rr][c4 * 4 + 2] = bf2f(v.z); qs[rr][c4 * 4 + 3] = bf2f(v.w);
    }
#pragma unroll
    for (int i = 0; i < 8; ++i) {
        int idx = i * 256 + t;
        int rr = idx >> 4, c4 = idx & 15;
        ushort4 v = *(const ushort4*)(Kt + (size_t)rr * 4096 + cb + j0 + c4 * 4);
        ks[rr][c4 * 4 + 0] = bf2f(v.x); ks[rr][c4 * 4 + 1] = bf2f(v.y);
        ks[rr][c4 * 4 + 2] = bf2f(v.z); ks[rr][c4 * 4 + 3] = bf2f(v.w);
    }
    __syncthreads();
    float acc[4][4] = {};
    for (int m = 0; m < 128; ++m) {
        float kv[4];
#pragma unroll
        for (int jj = 0; jj < 4; ++jj) kv[jj] = ks[m][tj * 4 + jj];
#pragma unroll
        for (int ii = 0; ii < 4; ++ii) {
            float qv = qs[ti * 4 + ii][m];
#pragma unroll
            for (int jj = 0; jj < 4; ++jj) acc[ii][jj] += qv * kv[jj];
        }
    }
#pragma unroll
    for (int ii = 0; ii < 4; ++ii) {
        int gi = i0 + ti * 4 + ii;
        u16 w[4];
#pragma unroll
        for (int jj = 0; jj < 4; ++jj) {
            int gj = j0 + tj * 4 + jj;
            float val = (gi >= gj) ? acc[ii][jj] * SCALEF : 0.f;
            w[jj] = f2bf(val);
        }
        *(ushort4*)(AcatOut + (size_t)(cb + gi) * 384 + j0 + tj * 4)
            = make_ushort4(w[0], w[1], w[2], w[3]);
    }
}

// --------------------------------------------------- sequential S recurrence
__global__ __launch_bounds__(256) void recur_k(const float* __restrict__ KtVp,
                                               const float* __restrict__ Mp,
                                               u16* __restrict__ SstT) {
    int blk = blockIdx.x;                 // 0..31
    int b = blk >> 4, dblk = blk & 15;
    int d0 = dblk * 64;
    int t = threadIdx.x, ti = t >> 4, tj = t & 15;
    __shared__ float S[128][64];
    __shared__ float Msm[128][32];
    for (int i = t; i < 128 * 64; i += 256) ((float*)S)[i] = 0.f;
    __syncthreads();
    for (int c = 0; c < 8; ++c) {
        int bc = b * 8 + c;
        for (int i = 0; i < 32; ++i) {
            int idx = i * 256 + t;
            int dl = idx >> 7, k = idx & 127;
            SstT[((size_t)bc * 1024 + d0 + dl) * 128 + k] = f2bf(S[k][dl]);
        }
        if (c == 7) break;
        const float* Mrow = Mp + (size_t)bc * 16384;
        float acc[8][4] = {};
        for (int kb = 0; kb < 4; ++kb) {
            for (int i = 0; i < 16; ++i) {
                int idx = i * 256 + t;
                int rr = idx >> 5, kk = idx & 31;
                Msm[rr][kk] = Mrow[(size_t)rr * 128 + kb * 32 + kk];
            }
            __syncthreads();
            for (int kk = 0; kk < 32; ++kk) {
                int k = kb * 32 + kk;
                float sv[4];
#pragma unroll
                for (int jj = 0; jj < 4; ++jj) sv[jj] = S[k][tj * 4 + jj];
#pragma unroll
                for (int ii = 0; ii < 8; ++ii) {
                    float mv = Msm[ti * 8 + ii][kk];
#pragma unroll
                    for (int jj = 0; jj < 4; ++jj) acc[ii][jj] += mv * sv[jj];
                }
            }
            __syncthreads();
        }
        const float* Kv = KtVp + (size_t)bc * 131072;
#pragma unroll
        for (int ii = 0; ii < 8; ++ii)
#pragma unroll
            for (int jj = 0; jj < 4; ++jj) {
                int i = ti * 8 + ii, j = tj * 4 + jj;
                S[i][j] += Kv[(size_t)i * 1024 + d0 + j] - acc[ii][jj];
            }
        __syncthreads();
    }
}

// ------------------------------------------------------------------- LayerNorm
__global__ __launch_bounds__(256) void ln_k(const float* __restrict__ h,
                                            const float* __restrict__ g,
                                            const float* __restrict__ be,
                                            u16* __restrict__ hn) {
    int row = blockIdx.x, t = threadIdx.x;
    float4 v = ((const float4*)(h + (size_t)row * 1024))[t];
    __shared__ float red[4];
    float s = v.x + v.y + v.z + v.w;
#pragma unroll
    for (int o = 32; o; o >>= 1) s += __shfl_down(s, o, 64);
    if ((t & 63) == 0) red[t >> 6] = s;
    __syncthreads();
    float mu = (red[0] + red[1] + red[2] + red[3]) * (1.f / 1024.f);
    float dx = v.x - mu, dy = v.y - mu, dz = v.z - mu, dw = v.w - mu;
    float q = dx * dx + dy * dy + dz * dz + dw * dw;
    __syncthreads();
#pragma unroll
    for (int o = 32; o; o >>= 1) q += __shfl_down(q, o, 64);
    if ((t & 63) == 0) red[t >> 6] = q;
    __syncthreads();
    float var = (red[0] + red[1] + red[2] + red[3]) * (1.f / 1024.f);
    float r = rsqrtf(var + 1e-5f);   // rsqrt(inf)=0 reproduces the f32-ref overflow path
    float4 gg = ((const float4*)g)[t];
    float4 bb = ((const float4*)be)[t];
    ushort4 w = make_ushort4(f2bf(dx * r * gg.x + bb.x), f2bf(dy * r * gg.y + bb.y),
                             f2bf(dz * r * gg.z + bb.z), f2bf(dw * r * gg.w + bb.w));
    *(ushort4*)(hn + (size_t)row * 1024 + t * 4) = w;
}

// ============ 256^2 8-phase output GEMM, phase-skewed register pipeline =====
// r9: MfmaUtil pinned at 35% because each phase's MFMA waits on its OWN
// ds_reads (issue+latency serial after barrier). Now quadrants rotate
// [q42(prev), q00, q40, q02] so every MFMA consumes fragments read ONE phase
// earlier — ds_read latency hides under the previous MFMA cluster. Same
// registers, same r6 staging/vmcnt discipline, same XCD-L2 mapping.
#define ONT 16
__global__ __launch_bounds__(512, 2) void gemm_out8(const u16* __restrict__ A,
                                                    const u16* __restrict__ B,
                                                    const float* __restrict__ bias,
                                                    float* __restrict__ C) {
    __shared__ u16 lds[2][2][16384];   // [dbuf][A=0/B=1][256*64]
    int tid = threadIdx.x;
    int lane = tid & 63, wave = tid >> 6;
    int wm = wave >> 2, wn = wave & 3;

    int bid = blockIdx.x;
    int xcd = bid & 7;                   // XCD id (round-robin dispatch)
    int l   = bid >> 3;                  // 0..249 local to XCD
    int bm0 = (xcd * 2 + (l & 1)) * 256; // XCD owns two bm panels
    int bn0 = (l >> 1) * 256;            // walks 125 bn panels

    int srl = lane >> 3;                 // row-within-8 group
    int cp  = (lane & 7) ^ (srl & 7);    // inverse-swizzled k-chunk

    facc4 acc[8][4];
#pragma unroll
    for (int m = 0; m < 8; ++m)
#pragma unroll
        for (int n = 0; n < 4; ++n) acc[m][n] = (facc4){0.f, 0.f, 0.f, 0.f};

#define STAGE(mat, dbuf, h, tt, G, gbase)                                          \
    {                                                                              \
        _Pragma("unroll")                                                          \
        for (int it_ = 0; it_ < 2; ++it_) {                                        \
            int s_ = it_ * 8 + wave;                                               \
            const u16* src_ = (G) + (size_t)((gbase) + (h) * 128 + s_ * 8 + srl) * 1024 \
                              + (tt) * 64 + cp * 8;                                \
            gll16(src_, &lds[dbuf][mat][(h) * 8192 + s_ * 512]);                   \
        }                                                                          \
    }

#define LDA4(dst, cur, mlo)                                                        \
    {                                                                              \
        _Pragma("unroll")                                                          \
        for (int m_ = 0; m_ < 4; ++m_) {                                           \
            _Pragma("unroll")                                                      \
            for (int kk_ = 0; kk_ < 2; ++kk_) {                                    \
                int row_ = wm * 128 + ((mlo) + m_) * 16 + (lane & 15);             \
                int off_ = (row_ << 7) + (kk_ << 6) + ((lane >> 4) << 4);          \
                off_ ^= (row_ & 7) << 4;                                           \
                dst[m_ * 2 + kk_] = *(const bfrag8*)((const char*)&lds[cur][0][0] + off_); \
            }                                                                      \
        }                                                                          \
    }

#define LDB2(dst, cur, nlo)                                                        \
    {                                                                              \
        _Pragma("unroll")                                                          \
        for (int n_ = 0; n_ < 2; ++n_) {                                           \
            _Pragma("unroll")                                                      \
            for (int kk_ = 0; kk_ < 2; ++kk_) {                                    \
                int row_ = wn * 64 + ((nlo) + n_) * 16 + (lane & 15);              \
                int off_ = (row_ << 7) + (kk_ << 6) + ((lane >> 4) << 4);          \
                off_ ^= (row_ & 7) << 4;                                           \
                dst[n_ * 2 + kk_] = *(const bfrag8*)((const char*)&lds[cur][1][0] + off_); \
            }                                                                      \
        }                                                                          \
    }

#define MM16(af, bf, mlo, nlo)                                                     \
    {                                                                              \
        __builtin_amdgcn_s_setprio(1);                                             \
        _Pragma("unroll")                                                          \
        for (int m_ = 0; m_ < 4; ++m_) {                                           \
            _Pragma("unroll")                                                      \
            for (int n_ = 0; n_ < 2; ++n_) {                                       \
                _Pragma("unroll")                                                  \
                for (int kk_ = 0; kk_ < 2; ++kk_)                                  \
                    acc[(mlo) + m_][(nlo) + n_] = __builtin_amdgcn_mfma_f32_16x16x32_bf16( \
                        af[m_ * 2 + kk_], bf[n_ * 2 + kk_], acc[(mlo) + m_][(nlo) + n_], 0, 0, 0); \
            }                                                                      \
        }                                                                          \
        __builtin_amdgcn_s_setprio(0);                                             \
    }

    // prologue: tile0 all 4 halves + tile1 A halves; wait tile0 complete
    STAGE(0, 0, 0, 0, A, bm0);
    STAGE(0, 0, 1, 0, A, bm0);
    STAGE(1, 0, 0, 0, B, bn0);
    STAGE(1, 0, 1, 0, B, bn0);
    STAGE(0, 1, 0, 1, A, bm0);
    STAGE(0, 1, 1, 1, A, bm0);
    asm volatile("s_waitcnt vmcnt(4)" ::: "memory");
    __builtin_amdgcn_s_barrier();

    bfrag8 a0[8], a1[8], b0[4], b1[4];
    for (int t = 0; t < ONT; ++t) {
        int cur = t & 1, nxt = cur ^ 1;
        // ---- P1: read a0,b0(cur); MFMA q42 of tile t-1 (a1,b1 regs)
        LDA4(a0, cur, 0);
        LDB2(b0, cur, 0);
        if (t + 1 < ONT) STAGE(1, nxt, 0, t + 1, B, bn0);
        __builtin_amdgcn_s_barrier();
        if (t > 0) { MM16(a1, b1, 4, 2); }
        __builtin_amdgcn_s_barrier();
        // ---- P2: read a1(cur); MFMA q00 (a0,b0 read last phase)
        LDA4(a1, cur, 4);
        if (t + 1 < ONT) STAGE(1, nxt, 1, t + 1, B, bn0);
        __builtin_amdgcn_s_barrier();
        MM16(a0, b0, 0, 0);
        __builtin_amdgcn_s_barrier();
        // ---- P3: read b1(cur); MFMA q40 (A-region of cur free after P2)
        LDB2(b1, cur, 2);
        if (t + 2 < ONT) STAGE(0, cur, 0, t + 2, A, bm0);
        __builtin_amdgcn_s_barrier();
        MM16(a1, b0, 4, 0);
        __builtin_amdgcn_s_barrier();
        // ---- P4: MFMA q02 (b1 read last phase)
        if (t + 2 < ONT) {
            STAGE(0, cur, 1, t + 2, A, bm0);
            asm volatile("s_waitcnt vmcnt(4)" ::: "memory");
        } else {
            asm volatile("s_waitcnt vmcnt(0)" ::: "memory");
        }
        __builtin_amdgcn_s_barrier();
        MM16(a0, b1, 0, 2);
        __builtin_amdgcn_s_barrier();
    }
    // trailing q42 of tile ONT-1
    MM16(a1, b1, 4, 2);

    // ---------------- epilogue: LDS re-layout -> full-line NT float4 stores
    float bb[4];
#pragma unroll
    for (int n = 0; n < 4; ++n) bb[n] = bias[bn0 + wn * 64 + n * 16 + (lane & 15)];

    float* ldsf = (float*)&lds[0][0][0];           // 128 x 256 f32 = 128 KiB
#pragma unroll
    for (int p = 0; p < 2; ++p) {
        __syncthreads();
        if (wm == p) {
#pragma unroll
            for (int m = 0; m < 8; ++m)
#pragma unroll
                for (int n = 0; n < 4; ++n) {
                    int rbase = m * 16 + ((lane >> 4) << 2);
                    int cbase = wn * 64 + n * 16 + (lane & 15);
#pragma unroll
                    for (int j = 0; j < 4; ++j) {
                        int rr = rbase + j;
                        int cc = cbase ^ (((rr >> 2) & 1) << 4);   // 2-way max
                        ldsf[rr * 256 + cc] = acc[m][n][j] + bb[n];
                    }
                }
        }
        __syncthreads();
#pragma unroll
        for (int i = 0; i < 16; ++i) {
            int flat = i * 2048 + tid * 4;
            int row = flat >> 8, col = flat & 255;
            int cc = col ^ (((row >> 2) & 1) << 4);
            facc4 v = *(const facc4*)&ldsf[row * 256 + cc];
            size_t gaddr = (size_t)(bm0 + p * 128 + row) * 32000 + bn0 + col;
            __builtin_nontemporal_store(v, (facc4*)&C[gaddr]);
        }
    }
#undef STAGE
#undef LDA4
#undef LDB2
#undef MM16
}

// =========================================================================
extern "C" void kernel_launch(void* const* d_in, const int* in_sizes, int n_in,
                              void* d_out, int out_size, void* d_ws, size_t ws_size,
                              hipStream_t stream) {
    const int*   x    = (const int*)d_in[0];
    const float* emb  = (const float*)d_in[1];
    const float* Wq   = (const float*)d_in[2];
    const float* Wk   = (const float*)d_in[3];
    const float* Wv   = (const float*)d_in[4];
    const float* Wo   = (const float*)d_in[5];
    const float* Ub   = (const float*)d_in[6];
    const float* Vb   = (const float*)d_in[7];
    const float* lng  = (const float*)d_in[8];
    const float* lnb  = (const float*)d_in[9];
    const float* Wout = (const float*)d_in[10];
    const float* bout = (const float*)d_in[11];
    float* out = (float*)d_out;
    char* ws = (char*)d_ws;

    u16*   ctx   = (u16*)(ws + 0);              // [4096][1024] bf16
    u16*   Acat  = (u16*)(ws + 8388608);        // [4096][384]  bf16 (attn|q)
    u16*   Kt    = (u16*)(ws + 11534336);       // [128][4096]  bf16
    u16*   WqkT  = (u16*)(ws + 12582912);       // [256][1024]
    u16*   WvT   = (u16*)(ws + 13107200);       // [1024][1024]
    float* stbyp = (float*)(ws + 15269888);     // [16][1024]
    float* xpart = (float*)(ws + 15335424);     // [16][8][1024] f32 partial sums
    float* h     = (float*)(ws + 0);            // [4096][1024] f32 (alias, earlier dead)
    u16*   Vt    = (u16*)(ws + 16777216);       // [1024][4096] bf16
    u16*   WoT   = (u16*)(ws + 25165824);       // [1024][1024]
    u16*   WoutT = (u16*)(ws + 27262976);       // [32000][1024]
    float* KtVp  = (float*)(ws + 92798976);     // [16][128][1024]
    float* Mp    = (float*)(ws + 101187584);    // [16][128][128]
    u16*   SstT  = (u16*)(ws + 102236160);      // [16][1024][128] bf16
    u16*   outp  = (u16*)(ws + 106430464);      // [4096][1024] bf16
    u16*   hnb   = (u16*)(ws + 114819072);      // [4096][1024] bf16

    transpose_f2b<<<dim3(2, 16), 256, 0, stream>>>(Wq, WqkT, 1024, 128);
    transpose_f2b<<<dim3(2, 16), 256, 0, stream>>>(Wk, WqkT + 128 * 1024, 1024, 128);
    transpose_f2b<<<dim3(16, 16), 256, 0, stream>>>(Wv, WvT, 1024, 1024);
    transpose_f2b<<<dim3(16, 16), 256, 0, stream>>>(Wo, WoT, 1024, 1024);
    transpose_f2b<<<dim3(500, 16), 256, 0, stream>>>(Wout, WoutT, 1024, 32000);

    embed_ctx<<<4096, 256, 0, stream>>>(x, emb, ctx);
    xmean_part<<<128, 256, 0, stream>>>(ctx, xpart);
    states_k<<<2, 256, 0, stream>>>(xpart, Ub, Vb, stbyp);

    gemm_k<SelPlain, EpiQK><<<dim3(32, 2, 1), 256, 0, stream>>>(
        SelPlain{ctx, WqkT, 1024, 1024}, EpiQK{Acat, Kt}, 16);
    gemm_k<SelPlain, EpiVt><<<dim3(32, 8, 1), 256, 0, stream>>>(
        SelPlain{ctx, WvT, 1024, 1024}, EpiVt{Vt}, 16);
    attn_k<<<dim3(4, 4, 16), 256, 0, stream>>>(Acat, Kt, Acat);
    gemm_k<SelKtKV, EpiKtKV><<<dim3(1, 9, 16), 256, 0, stream>>>(
        SelKtKV{Kt, Vt}, EpiKtKV{KtVp, Mp}, 4);
    recur_k<<<32, 256, 0, stream>>>(KtVp, Mp, SstT);
    gemm_k<SelComb, EpiComb><<<dim3(2, 8, 16), 256, 0, stream>>>(
        SelComb{Acat, Vt, SstT}, EpiComb{outp, stbyp}, 6);
    gemm_k<SelPlain, EpiF32><<<dim3(32, 8, 1), 256, 0, stream>>>(
        SelPlain{outp, WoT, 1024, 1024}, EpiF32{h, 1024}, 16);
    ln_k<<<4096, 256, 0, stream>>>(h, lng, lnb, hnb);
    // logits = hn @ Wout + bout
    gemm_out8<<<2000, 512, 0, stream>>>(hnb, WoutT, bout, out);
}

// Round 11
// 598.768 us; speedup vs baseline: 1.2413x; 1.2413x over previous
//
#include <hip/hip_runtime.h>

typedef unsigned short u16;
typedef __attribute__((ext_vector_type(8))) short bfrag8;   // 8 bf16 (4 VGPR)
typedef __attribute__((ext_vector_type(4))) float facc4;    // 4 f32 accum

#define SCALEF 0.08838834764831845f   // 1/sqrt(128)
#define LAMV   0.9f

__device__ __forceinline__ u16 f2bf(float f) {
    union { float f; unsigned u; } c; c.f = f;
    unsigned r = 0x7fffu + ((c.u >> 16) & 1u);
    return (u16)((c.u + r) >> 16);
}
__device__ __forceinline__ float bf2f(u16 h) {
    union { unsigned u; float f; } c; c.u = ((unsigned)h) << 16;
    return c.f;
}

__device__ __forceinline__ void gll16(const u16* g, u16* l) {
    __builtin_amdgcn_global_load_lds(
        (const __attribute__((address_space(1))) void*)g,
        (__attribute__((address_space(3))) void*)l, 16, 0, 0);
}

// ---------------------------------------------------------------- transpose
// NT loads (r6/r8 A/B: removing them cost ~55us in the non-gemm remainder)
__global__ __launch_bounds__(256) void transpose_f2b(const float* __restrict__ src,
                                                     u16* __restrict__ dst, int R, int C) {
    __shared__ float tile[64][65];
    int c0 = blockIdx.x * 64, r0 = blockIdx.y * 64;
    int t = threadIdx.x, tc = t & 63, tg = t >> 6;
#pragma unroll
    for (int i = 0; i < 16; ++i) {
        int rr = i * 4 + tg;
        tile[rr][tc] = __builtin_nontemporal_load(&src[(size_t)(r0 + rr) * C + c0 + tc]);
    }
    __syncthreads();
#pragma unroll
    for (int i = 0; i < 16; ++i) {
        int cc = i * 4 + tg;
        dst[(size_t)(c0 + cc) * R + r0 + tc] = f2bf(tile[tc][cc]);
    }
}

// ------------------------------------------------------------ embedding+ctx
__global__ __launch_bounds__(256) void embed_ctx(const int* __restrict__ x,
                                                 const float* __restrict__ emb,
                                                 u16* __restrict__ ctx) {
    int row = blockIdx.x;            // 0..4095
    int b = row >> 11, s = row & 2047;
    int t = threadIdx.x;
    float a0 = 0, a1 = 0, a2 = 0, a3 = 0;
    for (int off = 0; off < 4; ++off) {
        int ss = s - off;
        if (ss < 0) break;
        int tok = x[b * 2048 + ss];
        float4 v = ((const float4*)(emb + (size_t)tok * 1024))[t];
        a0 += v.x; a1 += v.y; a2 += v.z; a3 += v.w;
    }
    ushort4 w = make_ushort4(f2bf(a0), f2bf(a1), f2bf(a2), f2bf(a3));
    *(ushort4*)(ctx + (size_t)row * 1024 + t * 4) = w;
}

// ------------------------------------------- xmean partial sums (128 blocks)
__global__ __launch_bounds__(256) void xmean_part(const u16* __restrict__ ctx,
                                                  float* __restrict__ xpart) {
    int blk = blockIdx.x;            // bc*8 + g
    int bc = blk >> 3, g = blk & 7;
    int t = threadIdx.x;
    int row0 = (bc >> 3) * 2048 + (bc & 7) * 256 + g * 32;
    float a0 = 0, a1 = 0, a2 = 0, a3 = 0;
    for (int i = 0; i < 32; ++i) {
        ushort4 v = *(const ushort4*)(ctx + (size_t)(row0 + i) * 1024 + t * 4);
        a0 += bf2f(v.x); a1 += bf2f(v.y); a2 += bf2f(v.z); a3 += bf2f(v.w);
    }
    *(float4*)(xpart + (size_t)blk * 1024 + t * 4) = make_float4(a0, a1, a2, a3);
}

// --------------------------------------------------- EMA state + bypass term
__global__ __launch_bounds__(256) void states_k(const float* __restrict__ xpart,
                                                const float* __restrict__ Ub,
                                                const float* __restrict__ Vb,
                                                float* __restrict__ stbyp) {
    int b = blockIdx.x;
    int t = threadIdx.x, lane = t & 63, wave = t >> 6;
    __shared__ float xm[8][1024];
    __shared__ float byp[8][8];
    for (int idx = t; idx < 8 * 1024; idx += 256) {
        int c = idx >> 10, d = idx & 1023;
        float s = 0.f;
#pragma unroll
        for (int g = 0; g < 8; ++g)
            s += xpart[((size_t)(b * 8 + c) * 8 + g) * 1024 + d];
        xm[c][d] = s * (1.f / 256.f);
    }
    if (t < 8) byp[0][t] = 0.f;
    __syncthreads();
    for (int p = wave; p < 56; p += 4) {
        int c = 1 + (p >> 3), kr = p & 7;
        float s = 0;
        for (int d = lane; d < 1024; d += 64) s += xm[c - 1][d] * Ub[d * 8 + kr];
#pragma unroll
        for (int o = 32; o; o >>= 1) s += __shfl_down(s, o, 64);
        if (lane == 0) byp[c][kr] = s;
    }
    __syncthreads();
    for (int d = t; d < 1024; d += 256) {
        float st = 0.f;
        for (int c = 0; c < 8; ++c) {
            float bv = 0.f;
#pragma unroll
            for (int kr = 0; kr < 8; ++kr) bv += byp[c][kr] * Vb[kr * 1024 + d];
            stbyp[((size_t)b * 8 + c) * 1024 + d] = st + bv;
            st = LAMV * st + (1.0f - LAMV) * xm[c][d];
        }
    }
}

// --------------------------------------------------------------- GEMM core (128^2, small ops)
struct TileSrc { const u16* a; int lda; const u16* b; int ldb; };

template <class Sel, class Epi>
__global__ __launch_bounds__(256) void gemm_k(Sel sel, Epi epi, int KT) {
    __shared__ u16 As[8192];
    __shared__ u16 Bs[8192];
    int t = threadIdx.x, lane = t & 63, wave = t >> 6;
    int wm = wave >> 1, wn = wave & 1;
    int m0 = blockIdx.x * 128, n0 = blockIdx.y * 128, bc = blockIdx.z;

    facc4 acc[4][4];
#pragma unroll
    for (int i = 0; i < 4; ++i)
#pragma unroll
        for (int j = 0; j < 4; ++j) acc[i][j] = (facc4){0.f, 0.f, 0.f, 0.f};

    for (int kt = 0; kt < KT; ++kt) {
        TileSrc s = sel(m0, n0, bc, kt);
#pragma unroll
        for (int it = 0; it < 4; ++it) {
            int q = (it * 4 + wave) * 64 + lane;
            int L = q << 4;                        // linear LDS byte
            int r = L >> 7;                        // tile row
            int cp = ((L >> 4) & 7) ^ (r & 7);     // inverse-swizzled k-chunk
            const u16* ga = s.a + (size_t)r * s.lda + cp * 8;
            const u16* gb = s.b + (size_t)r * s.ldb + cp * 8;
            gll16(ga, As + (size_t)(it * 4 + wave) * 512);
            gll16(gb, Bs + (size_t)(it * 4 + wave) * 512);
        }
        __syncthreads();
#pragma unroll
        for (int kk = 0; kk < 2; ++kk) {
            bfrag8 af[4], bfr[4];
#pragma unroll
            for (int i = 0; i < 4; ++i) {
                int row = wm * 64 + i * 16 + (lane & 15);
                int off = (row << 7) + kk * 64 + ((lane >> 4) << 4);
                off ^= (row & 7) << 4;
                af[i] = *(const bfrag8*)((const char*)As + off);
            }
#pragma unroll
            for (int j = 0; j < 4; ++j) {
                int row = wn * 64 + j * 16 + (lane & 15);
                int off = (row << 7) + kk * 64 + ((lane >> 4) << 4);
                off ^= (row & 7) << 4;
                bfr[j] = *(const bfrag8*)((const char*)Bs + off);
            }
#pragma unroll
            for (int i = 0; i < 4; ++i)
#pragma unroll
                for (int j = 0; j < 4; ++j)
                    acc[i][j] = __builtin_amdgcn_mfma_f32_16x16x32_bf16(af[i], bfr[j], acc[i][j], 0, 0, 0);
        }
        __syncthreads();
    }
#pragma unroll
    for (int i = 0; i < 4; ++i)
#pragma unroll
        for (int j = 0; j < 4; ++j) {
            int row0 = m0 + wm * 64 + i * 16 + ((lane >> 4) << 2);
            int col  = n0 + wn * 64 + j * 16 + (lane & 15);
            epi.store(bc, row0, col, acc[i][j]);
        }
}

// --------------------------------------------------------------- selectors
struct SelPlain {
    const u16 *A, *B; int lda, ldb;
    __device__ TileSrc operator()(int m0, int n0, int bc, int kt) const {
        return TileSrc{A + (size_t)m0 * lda + kt * 64, lda,
                       B + (size_t)n0 * ldb + kt * 64, ldb};
    }
};
struct SelKtKV {
    const u16 *Kt, *Vt;
    __device__ TileSrc operator()(int m0, int n0, int bc, int kt) const {
        int cb = (bc >> 3) * 2048 + (bc & 7) * 256;
        const u16* a = Kt + (size_t)m0 * 4096 + cb + kt * 64;
        const u16* b = (n0 < 1024 ? Vt + (size_t)n0 * 4096
                                  : Kt + (size_t)(n0 - 1024) * 4096) + cb + kt * 64;
        return TileSrc{a, 4096, b, 4096};
    }
};
struct SelComb {
    const u16 *Acat, *Vt, *SstT;
    __device__ TileSrc operator()(int m0, int n0, int bc, int kt) const {
        int cb = (bc >> 3) * 2048 + (bc & 7) * 256;
        const u16* a = Acat + (size_t)(cb + m0) * 384 + kt * 64;
        const u16* b; int ldb;
        if (kt < 4) { b = Vt + (size_t)n0 * 4096 + cb + kt * 64; ldb = 4096; }
        else        { b = SstT + ((size_t)bc * 1024 + n0) * 128 + (kt - 4) * 64; ldb = 128; }
        return TileSrc{a, 384, b, ldb};
    }
};

// --------------------------------------------------------------- epilogues
struct EpiQK {
    u16 *Acat, *Kt;
    __device__ void store(int bc, int row0, int col, facc4 v) const {
        float p[4];
#pragma unroll
        for (int j = 0; j < 4; ++j) { float x = v[j]; p[j] = x > 0.f ? x + 1.f : __expf(x); }
        if (col < 128) {
#pragma unroll
            for (int j = 0; j < 4; ++j) Acat[(size_t)(row0 + j) * 384 + 256 + col] = f2bf(p[j]);
        } else {
            ushort4 w = make_ushort4(f2bf(p[0]), f2bf(p[1]), f2bf(p[2]), f2bf(p[3]));
            *(ushort4*)(Kt + (size_t)(col - 128) * 4096 + row0) = w;
        }
    }
};
struct EpiVt {
    u16* Vt;
    __device__ void store(int bc, int row0, int col, facc4 v) const {
        ushort4 w = make_ushort4(f2bf(v[0]), f2bf(v[1]), f2bf(v[2]), f2bf(v[3]));
        *(ushort4*)(Vt + (size_t)col * 4096 + row0) = w;
    }
};
struct EpiKtKV {
    float *KtVp, *Mp;
    __device__ void store(int bc, int row0, int col, facc4 v) const {
        if (col < 1024) {
            float* p = KtVp + (size_t)bc * 131072;
#pragma unroll
            for (int j = 0; j < 4; ++j) p[(size_t)(row0 + j) * 1024 + col] = v[j] * SCALEF;
        } else {
            float* p = Mp + (size_t)bc * 16384;
#pragma unroll
            for (int j = 0; j < 4; ++j) p[(size_t)(row0 + j) * 128 + (col - 1024)] = v[j] * SCALEF;
        }
    }
};
struct EpiComb {
    u16* outp; const float* stbyp;
    __device__ void store(int bc, int row0, int col, facc4 v) const {
        int cb = (bc >> 3) * 2048 + (bc & 7) * 256;
        float sb = stbyp[(size_t)bc * 1024 + col];
#pragma unroll
        for (int j = 0; j < 4; ++j) outp[(size_t)(cb + row0 + j) * 1024 + col] = f2bf(v[j] + sb);
    }
};
struct EpiF32 {
    float* C; int ld;
    __device__ void store(int bc, int row0, int col, facc4 v) const {
#pragma unroll
        for (int j = 0; j < 4; ++j) C[(size_t)(row0 + j) * ld + col] = v[j];
    }
};

// ------------------------------------------------------ intra-chunk attention
__global__ __launch_bounds__(256) void attn_k(const u16* __restrict__ Acat,
                                              const u16* __restrict__ Kt,
                                              u16* __restrict__ AcatOut) {
    int bx = blockIdx.x, by = blockIdx.y, bc = blockIdx.z;
    int cb = (bc >> 3) * 2048 + (bc & 7) * 256;
    int i0 = bx * 64, j0 = by * 64;
    int t = threadIdx.x, ti = t >> 4, tj = t & 15;
    if (by > bx) {
        ushort4 z = make_ushort4(0, 0, 0, 0);
#pragma unroll
        for (int ii = 0; ii < 4; ++ii) {
            int gi = i0 + ti * 4 + ii;
            *(ushort4*)(AcatOut + (size_t)(cb + gi) * 384 + j0 + tj * 4) = z;
        }
        return;
    }
    __shared__ float qs[64][128];
    __shared__ float ks[128][64];
#pragma unroll
    for (int i = 0; i < 8; ++i) {
        int idx = i * 256 + t;
        int rr = idx >> 5, c4 = idx & 31;
        ushort4 v = *(const ushort4*)(Acat + (size_t)(cb + i0 + rr) * 384 + 256 + c4 * 4);
        qs[rr][c4 * 4 + 0] = bf2f(v.x); qs[rr][c4 * 4 + 1] = bf2f(v.y);
        qs[rr][c4 * 4 + 2] = bf2f(v.z); qs[rr][c4 * 4 + 3] = bf2f(v.w);
    }
#pragma unroll
    for (int i = 0; i < 8; ++i) {
        int idx = i * 256 + t;
        int rr = idx >> 4, c4 = idx & 15;
        ushort4 v = *(const ushort4*)(Kt + (size_t)rr * 4096 + cb + j0 + c4 * 4);
        ks[rr][c4 * 4 + 0] = bf2f(v.x); ks[rr][c4 * 4 + 1] = bf2f(v.y);
        ks[rr][c4 * 4 + 2] = bf2f(v.z); ks[rr][c4 * 4 + 3] = bf2f(v.w);
    }
    __syncthreads();
    float acc[4][4] = {};
    for (int m = 0; m < 128; ++m) {
        float kv[4];
#pragma unroll
        for (int jj = 0; jj < 4; ++jj) kv[jj] = ks[m][tj * 4 + jj];
#pragma unroll
        for (int ii = 0; ii < 4; ++ii) {
            float qv = qs[ti * 4 + ii][m];
#pragma unroll
            for (int jj = 0; jj < 4; ++jj) acc[ii][jj] += qv * kv[jj];
        }
    }
#pragma unroll
    for (int ii = 0; ii < 4; ++ii) {
        int gi = i0 + ti * 4 + ii;
        u16 w[4];
#pragma unroll
        for (int jj = 0; jj < 4; ++jj) {
            int gj = j0 + tj * 4 + jj;
            float val = (gi >= gj) ? acc[ii][jj] * SCALEF : 0.f;
            w[jj] = f2bf(val);
        }
        *(ushort4*)(AcatOut + (size_t)(cb + gi) * 384 + j0 + tj * 4)
            = make_ushort4(w[0], w[1], w[2], w[3]);
    }
}

// --------------------------------------------------- sequential S recurrence
__global__ __launch_bounds__(256) void recur_k(const float* __restrict__ KtVp,
                                               const float* __restrict__ Mp,
                                               u16* __restrict__ SstT) {
    int blk = blockIdx.x;                 // 0..31
    int b = blk >> 4, dblk = blk & 15;
    int d0 = dblk * 64;
    int t = threadIdx.x, ti = t >> 4, tj = t & 15;
    __shared__ float S[128][64];
    __shared__ float Msm[128][32];
    for (int i = t; i < 128 * 64; i += 256) ((float*)S)[i] = 0.f;
    __syncthreads();
    for (int c = 0; c < 8; ++c) {
        int bc = b * 8 + c;
        for (int i = 0; i < 32; ++i) {
            int idx = i * 256 + t;
            int dl = idx >> 7, k = idx & 127;
            SstT[((size_t)bc * 1024 + d0 + dl) * 128 + k] = f2bf(S[k][dl]);
        }
        if (c == 7) break;
        const float* Mrow = Mp + (size_t)bc * 16384;
        float acc[8][4] = {};
        for (int kb = 0; kb < 4; ++kb) {
            for (int i = 0; i < 16; ++i) {
                int idx = i * 256 + t;
                int rr = idx >> 5, kk = idx & 31;
                Msm[rr][kk] = Mrow[(size_t)rr * 128 + kb * 32 + kk];
            }
            __syncthreads();
            for (int kk = 0; kk < 32; ++kk) {
                int k = kb * 32 + kk;
                float sv[4];
#pragma unroll
                for (int jj = 0; jj < 4; ++jj) sv[jj] = S[k][tj * 4 + jj];
#pragma unroll
                for (int ii = 0; ii < 8; ++ii) {
                    float mv = Msm[ti * 8 + ii][kk];
#pragma unroll
                    for (int jj = 0; jj < 4; ++jj) acc[ii][jj] += mv * sv[jj];
                }
            }
            __syncthreads();
        }
        const float* Kv = KtVp + (size_t)bc * 131072;
#pragma unroll
        for (int ii = 0; ii < 8; ++ii)
#pragma unroll
            for (int jj = 0; jj < 4; ++jj) {
                int i = ti * 8 + ii, j = tj * 4 + jj;
                S[i][j] += Kv[(size_t)i * 1024 + d0 + j] - acc[ii][jj];
            }
        __syncthreads();
    }
}

// ------------------------------------------------------------------- LayerNorm
__global__ __launch_bounds__(256) void ln_k(const float* __restrict__ h,
                                            const float* __restrict__ g,
                                            const float* __restrict__ be,
                                            u16* __restrict__ hn) {
    int row = blockIdx.x, t = threadIdx.x;
    float4 v = ((const float4*)(h + (size_t)row * 1024))[t];
    __shared__ float red[4];
    float s = v.x + v.y + v.z + v.w;
#pragma unroll
    for (int o = 32; o; o >>= 1) s += __shfl_down(s, o, 64);
    if ((t & 63) == 0) red[t >> 6] = s;
    __syncthreads();
    float mu = (red[0] + red[1] + red[2] + red[3]) * (1.f / 1024.f);
    float dx = v.x - mu, dy = v.y - mu, dz = v.z - mu, dw = v.w - mu;
    float q = dx * dx + dy * dy + dz * dz + dw * dw;
    __syncthreads();
#pragma unroll
    for (int o = 32; o; o >>= 1) q += __shfl_down(q, o, 64);
    if ((t & 63) == 0) red[t >> 6] = q;
    __syncthreads();
    float var = (red[0] + red[1] + red[2] + red[3]) * (1.f / 1024.f);
    float r = rsqrtf(var + 1e-5f);   // rsqrt(inf)=0 reproduces the f32-ref overflow path
    float4 gg = ((const float4*)g)[t];
    float4 bb = ((const float4*)be)[t];
    ushort4 w = make_ushort4(f2bf(dx * r * gg.x + bb.x), f2bf(dy * r * gg.y + bb.y),
                             f2bf(dz * r * gg.z + bb.z), f2bf(dw * r * gg.w + bb.w));
    *(ushort4*)(hn + (size_t)row * 1024 + t * 4) = w;
}

// ===================== 256^2 8-phase output GEMM (r9 config, stage-first) ===
// C[4096 x 32000] = A[4096x1024]·B^T + bias. r9 = best known (320us, 860TF).
// r10's phase-skew regressed (455us) -> reverted. Only change vs r9: STAGE
// issued before the phase's ds_reads (T14 issue-early; hazard-free since the
// staged region was proven free by the previous phase's barrier).
#define ONT 16
__global__ __launch_bounds__(512, 2) void gemm_out8(const u16* __restrict__ A,
                                                    const u16* __restrict__ B,
                                                    const float* __restrict__ bias,
                                                    float* __restrict__ C) {
    __shared__ u16 lds[2][2][16384];   // [dbuf][A=0/B=1][256*64]
    int tid = threadIdx.x;
    int lane = tid & 63, wave = tid >> 6;
    int wm = wave >> 2, wn = wave & 3;

    int bid = blockIdx.x;
    int xcd = bid & 7;                   // XCD id (round-robin dispatch, m09)
    int l   = bid >> 3;                  // 0..249 local to XCD
    int bm0 = (xcd * 2 + (l & 1)) * 256; // XCD owns two bm panels (1MB A in L2)
    int bn0 = (l >> 1) * 256;            // walks 125 bn panels

    int srl = lane >> 3;                 // row-within-8 group
    int cp  = (lane & 7) ^ (srl & 7);    // inverse-swizzled k-chunk

    facc4 acc[8][4];
#pragma unroll
    for (int m = 0; m < 8; ++m)
#pragma unroll
        for (int n = 0; n < 4; ++n) acc[m][n] = (facc4){0.f, 0.f, 0.f, 0.f};

#define STAGE(mat, dbuf, h, tt, G, gbase)                                          \
    {                                                                              \
        _Pragma("unroll")                                                          \
        for (int it_ = 0; it_ < 2; ++it_) {                                        \
            int s_ = it_ * 8 + wave;                                               \
            const u16* src_ = (G) + (size_t)((gbase) + (h) * 128 + s_ * 8 + srl) * 1024 \
                              + (tt) * 64 + cp * 8;                                \
            gll16(src_, &lds[dbuf][mat][(h) * 8192 + s_ * 512]);                   \
        }                                                                          \
    }

#define LDA4(dst, cur, mlo)                                                        \
    {                                                                              \
        _Pragma("unroll")                                                          \
        for (int m_ = 0; m_ < 4; ++m_) {                                           \
            _Pragma("unroll")                                                      \
            for (int kk_ = 0; kk_ < 2; ++kk_) {                                    \
                int row_ = wm * 128 + ((mlo) + m_) * 16 + (lane & 15);             \
                int off_ = (row_ << 7) + (kk_ << 6) + ((lane >> 4) << 4);          \
                off_ ^= (row_ & 7) << 4;                                           \
                dst[m_ * 2 + kk_] = *(const bfrag8*)((const char*)&lds[cur][0][0] + off_); \
            }                                                                      \
        }                                                                          \
    }

#define LDB2(dst, cur, nlo)                                                        \
    {                                                                              \
        _Pragma("unroll")                                                          \
        for (int n_ = 0; n_ < 2; ++n_) {                                           \
            _Pragma("unroll")                                                      \
            for (int kk_ = 0; kk_ < 2; ++kk_) {                                    \
                int row_ = wn * 64 + ((nlo) + n_) * 16 + (lane & 15);              \
                int off_ = (row_ << 7) + (kk_ << 6) + ((lane >> 4) << 4);          \
                off_ ^= (row_ & 7) << 4;                                           \
                dst[n_ * 2 + kk_] = *(const bfrag8*)((const char*)&lds[cur][1][0] + off_); \
            }                                                                      \
        }                                                                          \
    }

#define MM16(af, bf, mlo, nlo)                                                     \
    {                                                                              \
        __builtin_amdgcn_s_setprio(1);                                             \
        _Pragma("unroll")                                                          \
        for (int m_ = 0; m_ < 4; ++m_) {                                           \
            _Pragma("unroll")                                                      \
            for (int n_ = 0; n_ < 2; ++n_) {                                       \
                _Pragma("unroll")                                                  \
                for (int kk_ = 0; kk_ < 2; ++kk_)                                  \
                    acc[(mlo) + m_][(nlo) + n_] = __builtin_amdgcn_mfma_f32_16x16x32_bf16( \
                        af[m_ * 2 + kk_], bf[n_ * 2 + kk_], acc[(mlo) + m_][(nlo) + n_], 0, 0, 0); \
            }                                                                      \
        }                                                                          \
        __builtin_amdgcn_s_setprio(0);                                             \
    }

    // prologue: tile0 all 4 halves + tile1 A halves; wait tile0 complete
    STAGE(0, 0, 0, 0, A, bm0);
    STAGE(0, 0, 1, 0, A, bm0);
    STAGE(1, 0, 0, 0, B, bn0);
    STAGE(1, 0, 1, 0, B, bn0);
    STAGE(0, 1, 0, 1, A, bm0);
    STAGE(0, 1, 1, 1, A, bm0);
    asm volatile("s_waitcnt vmcnt(4)" ::: "memory");
    __builtin_amdgcn_s_barrier();

    bfrag8 a0[8], a1[8], b0[4], b1[4];
    for (int t = 0; t < ONT; ++t) {
        int cur = t & 1, nxt = cur ^ 1;
        // ---- P1 (stage first: loads enter memory system earlier)
        if (t + 1 < ONT) STAGE(1, nxt, 0, t + 1, B, bn0);
        LDA4(a0, cur, 0);
        LDB2(b0, cur, 0);
        __builtin_amdgcn_s_barrier();
        MM16(a0, b0, 0, 0);
        __builtin_amdgcn_s_barrier();
        // ---- P2
        if (t + 1 < ONT) STAGE(1, nxt, 1, t + 1, B, bn0);
        LDA4(a1, cur, 4);
        __builtin_amdgcn_s_barrier();
        MM16(a1, b0, 4, 0);
        __builtin_amdgcn_s_barrier();
        // ---- P3 (A-region of cur fully read after P2 -> stage A(t+2))
        if (t + 2 < ONT) STAGE(0, cur, 0, t + 2, A, bm0);
        LDB2(b1, cur, 2);
        __builtin_amdgcn_s_barrier();
        MM16(a0, b1, 0, 2);
        __builtin_amdgcn_s_barrier();
        // ---- P4
        if (t + 2 < ONT) {
            STAGE(0, cur, 1, t + 2, A, bm0);
            asm volatile("s_waitcnt vmcnt(4)" ::: "memory");
        } else {
            asm volatile("s_waitcnt vmcnt(0)" ::: "memory");
        }
        __builtin_amdgcn_s_barrier();
        MM16(a1, b1, 4, 2);
        __builtin_amdgcn_s_barrier();
    }

    // ---------------- epilogue: LDS re-layout -> full-line NT float4 stores
    float bb[4];
#pragma unroll
    for (int n = 0; n < 4; ++n) bb[n] = bias[bn0 + wn * 64 + n * 16 + (lane & 15)];

    float* ldsf = (float*)&lds[0][0][0];           // 128 x 256 f32 = 128 KiB
#pragma unroll
    for (int p = 0; p < 2; ++p) {
        __syncthreads();
        if (wm == p) {
#pragma unroll
            for (int m = 0; m < 8; ++m)
#pragma unroll
                for (int n = 0; n < 4; ++n) {
                    int rbase = m * 16 + ((lane >> 4) << 2);
                    int cbase = wn * 64 + n * 16 + (lane & 15);
#pragma unroll
                    for (int j = 0; j < 4; ++j) {
                        int rr = rbase + j;
                        int cc = cbase ^ (((rr >> 2) & 1) << 4);   // 2-way max
                        ldsf[rr * 256 + cc] = acc[m][n][j] + bb[n];
                    }
                }
        }
        __syncthreads();
#pragma unroll
        for (int i = 0; i < 16; ++i) {
            int flat = i * 2048 + tid * 4;
            int row = flat >> 8, col = flat & 255;
            int cc = col ^ (((row >> 2) & 1) << 4);
            facc4 v = *(const facc4*)&ldsf[row * 256 + cc];
            size_t gaddr = (size_t)(bm0 + p * 128 + row) * 32000 + bn0 + col;
            __builtin_nontemporal_store(v, (facc4*)&C[gaddr]);
        }
    }
#undef STAGE
#undef LDA4
#undef LDB2
#undef MM16
}

// =========================================================================
extern "C" void kernel_launch(void* const* d_in, const int* in_sizes, int n_in,
                              void* d_out, int out_size, void* d_ws, size_t ws_size,
                              hipStream_t stream) {
    const int*   x    = (const int*)d_in[0];
    const float* emb  = (const float*)d_in[1];
    const float* Wq   = (const float*)d_in[2];
    const float* Wk   = (const float*)d_in[3];
    const float* Wv   = (const float*)d_in[4];
    const float* Wo   = (const float*)d_in[5];
    const float* Ub   = (const float*)d_in[6];
    const float* Vb   = (const float*)d_in[7];
    const float* lng  = (const float*)d_in[8];
    const float* lnb  = (const float*)d_in[9];
    const float* Wout = (const float*)d_in[10];
    const float* bout = (const float*)d_in[11];
    float* out = (float*)d_out;
    char* ws = (char*)d_ws;

    u16*   ctx   = (u16*)(ws + 0);              // [4096][1024] bf16
    u16*   Acat  = (u16*)(ws + 8388608);        // [4096][384]  bf16 (attn|q)
    u16*   Kt    = (u16*)(ws + 11534336);       // [128][4096]  bf16
    u16*   WqkT  = (u16*)(ws + 12582912);       // [256][1024]
    u16*   WvT   = (u16*)(ws + 13107200);       // [1024][1024]
    float* stbyp = (float*)(ws + 15269888);     // [16][1024]
    float* xpart = (float*)(ws + 15335424);     // [16][8][1024] f32 partial sums
    float* h     = (float*)(ws + 0);            // [4096][1024] f32 (alias, earlier dead)
    u16*   Vt    = (u16*)(ws + 16777216);       // [1024][4096] bf16
    u16*   WoT   = (u16*)(ws + 25165824);       // [1024][1024]
    u16*   WoutT = (u16*)(ws + 27262976);       // [32000][1024]
    float* KtVp  = (float*)(ws + 92798976);     // [16][128][1024]
    float* Mp    = (float*)(ws + 101187584);    // [16][128][128]
    u16*   SstT  = (u16*)(ws + 102236160);      // [16][1024][128] bf16
    u16*   outp  = (u16*)(ws + 106430464);      // [4096][1024] bf16
    u16*   hnb   = (u16*)(ws + 114819072);      // [4096][1024] bf16

    transpose_f2b<<<dim3(2, 16), 256, 0, stream>>>(Wq, WqkT, 1024, 128);
    transpose_f2b<<<dim3(2, 16), 256, 0, stream>>>(Wk, WqkT + 128 * 1024, 1024, 128);
    transpose_f2b<<<dim3(16, 16), 256, 0, stream>>>(Wv, WvT, 1024, 1024);
    transpose_f2b<<<dim3(16, 16), 256, 0, stream>>>(Wo, WoT, 1024, 1024);
    transpose_f2b<<<dim3(500, 16), 256, 0, stream>>>(Wout, WoutT, 1024, 32000);

    embed_ctx<<<4096, 256, 0, stream>>>(x, emb, ctx);
    xmean_part<<<128, 256, 0, stream>>>(ctx, xpart);
    states_k<<<2, 256, 0, stream>>>(xpart, Ub, Vb, stbyp);

    gemm_k<SelPlain, EpiQK><<<dim3(32, 2, 1), 256, 0, stream>>>(
        SelPlain{ctx, WqkT, 1024, 1024}, EpiQK{Acat, Kt}, 16);
    gemm_k<SelPlain, EpiVt><<<dim3(32, 8, 1), 256, 0, stream>>>(
        SelPlain{ctx, WvT, 1024, 1024}, EpiVt{Vt}, 16);
    attn_k<<<dim3(4, 4, 16), 256, 0, stream>>>(Acat, Kt, Acat);
    gemm_k<SelKtKV, EpiKtKV><<<dim3(1, 9, 16), 256, 0, stream>>>(
        SelKtKV{Kt, Vt}, EpiKtKV{KtVp, Mp}, 4);
    recur_k<<<32, 256, 0, stream>>>(KtVp, Mp, SstT);
    gemm_k<SelComb, EpiComb><<<dim3(2, 8, 16), 256, 0, stream>>>(
        SelComb{Acat, Vt, SstT}, EpiComb{outp, stbyp}, 6);
    gemm_k<SelPlain, EpiF32><<<dim3(32, 8, 1), 256, 0, stream>>>(
        SelPlain{outp, WoT, 1024, 1024}, EpiF32{h, 1024}, 16);
    ln_k<<<4096, 256, 0, stream>>>(h, lng, lnb, hnb);
    // logits = hn @ Wout + bout
    gemm_out8<<<2000, 512, 0, stream>>>(hnb, WoutT, bout, out);
}